// Round 4
// baseline (490.044 us; speedup 1.0000x reference)
//
#include <hip/hip_runtime.h>
#include <hip/hip_bf16.h>

// ---------------------------------------------------------------------------
// MinigridPPOLSTMAgent forward, round 4: MFMA LSTM recurrence.
//   T=128, B=256, N=32768, HID=128, NFLAT=1024, NA=7
// Pipeline:
//   P1 prep_wih   : w_ih fp32 [512][co*16+p] -> fp16 wb[512][p*64+co] (K-perm)
//   P2 prep_convw : w2/w3 -> MFMA A-fragment-ordered fp16 tables
//   K1 conv_fused : obs -> featb[N][p*64+co] fp16 (conv2/3 via MFMA)
//   K3 gemm_mfma  : xperm = featb @ wb^T, epilogue scatters into the
//                   LSTM-lane-contiguous permuted layout (see below)
//   K4 lstm       : 16 blocks x 512thr; C[m=gate][n=batch] MFMA recurrence,
//                   w_hh frags in VGPRs, h k-major in 4KB LDS
//   K5 heads      : out[N,8] = hid @ [actor;critic].T + b
//
// xperm layout: value for (t, batch b, gate g):
//   bb=b>>4, col=b&15, gr=g>>7, u=g&127, w=u>>4, q=(u>>2)&3, rr=u&3
//   addr = (((t*16+bb)*8 + w)*64 + q*16 + col)*16 + gr*4 + rr
//   => LSTM lane l=q*16+col of wave w reads its 16 step-values contiguously.
// ---------------------------------------------------------------------------

#define N_IMG   32768
#define T_LEN   128
#define B_ENV   256
#define HID     128

typedef _Float16 f16x8 __attribute__((ext_vector_type(8)));
typedef float    f32x4 __attribute__((ext_vector_type(4)));
typedef unsigned short ushort8v __attribute__((ext_vector_type(8)));
typedef unsigned short ushort4v __attribute__((ext_vector_type(4)));

__device__ __forceinline__ float sigm_(float x) { return 1.0f / (1.0f + __expf(-x)); }
__device__ __forceinline__ float tanh_(float x) { return 2.0f / (1.0f + __expf(-2.0f * x)) - 1.0f; }

__device__ __forceinline__ unsigned short f2h(float x) {
    union { _Float16 h; unsigned short u; } un; un.h = (_Float16)x;
    return un.u;
}

#define GLDS16(g, l) __builtin_amdgcn_global_load_lds( \
    (const __attribute__((address_space(1))) unsigned int*)(g), \
    (__attribute__((address_space(3))) unsigned int*)(l), 16, 0, 0)

// ---------------------------------------------------------------------------
// P1: w_ih fp32 [n][k=co*16+p] -> fp16 wb[n][k'=p*64+co]
// ---------------------------------------------------------------------------
__global__ void prep_wih(const float* __restrict__ w, unsigned short* __restrict__ wb)
{
    const int idx = blockIdx.x * 256 + threadIdx.x;   // < 524288
    const int n = idx >> 10, kk = idx & 1023;
    const int p = kk >> 6, co = kk & 63;
    wb[idx] = f2h(w[n * 1024 + co * 16 + p]);
}

// ---------------------------------------------------------------------------
// P2: conv2/conv3 weights -> MFMA A-fragment layout (fp16)
// ---------------------------------------------------------------------------
__global__ void prep_convw(const float* __restrict__ w2, const float* __restrict__ w3,
                           unsigned short* __restrict__ wb2g, unsigned short* __restrict__ wb3g)
{
    const int t = blockIdx.x * 256 + threadIdx.x;     // < 10240
    if (t < 2048) {
        const int j = t & 7, lane = (t >> 3) & 63, f = t >> 9;   // f = ky*2+ct
        const int ky = f >> 1, ct = f & 1;
        const int k = ((lane >> 4) << 3) + j, kx = k >> 4, ci = k & 15;
        wb2g[t] = f2h(w2[(ct * 16 + (lane & 15)) * 64 + ci * 4 + ky * 2 + kx]);
    } else if (t < 10240) {
        const int u = t - 2048;
        const int j = u & 7, lane = (u >> 3) & 63, f = u >> 9;   // f = ct*4+pos
        const int ct = f >> 2, pos = f & 3;
        const int ci = ((lane >> 4) << 3) + j;
        wb3g[u] = f2h(w3[(ct * 16 + (lane & 15)) * 128 + ci * 4 + pos]);
    }
}

// ---------------------------------------------------------------------------
// K1: fused conv. 16 images / block, 2048 blocks, 256 thr (4 waves).
// ---------------------------------------------------------------------------
__global__ __launch_bounds__(256, 2) void conv_fused(
    const float* __restrict__ obs,
    const float* __restrict__ w1, const float* __restrict__ b1,
    const float* __restrict__ b2, const float* __restrict__ b3,
    const unsigned short* __restrict__ wb2g,
    const unsigned short* __restrict__ wb3g,
    unsigned short* __restrict__ featb)
{
    __shared__ __align__(16) unsigned char u1[25856];   // max(obs 9472, c2s 25856)
    __shared__ __align__(16) unsigned char u2[33024];   // max(c1s 18688, c3s 33024)
    __shared__ float w1s[192];
    __shared__ float b1s[16];

    float* s_obs = (float*)u1;                 // [img][148]
    unsigned short* c2s = (unsigned short*)u1; // [img][pix*32+ci], img stride 808
    unsigned short* c1s = (unsigned short*)u2; // [img][p*16+ci],  img stride 584
    unsigned short* c3s = (unsigned short*)u2; // [img][p*64+co],  img stride 1032

    const int tid = threadIdx.x, lane = tid & 63, wv = tid >> 6;
    const int base = blockIdx.x * 16;

    if (tid < 192) w1s[tid] = w1[tid];
    if (tid < 16)  b1s[tid] = b1[tid];
    for (int i = tid; i < 16 * 147; i += 256) {
        const int im = i / 147, r = i - im * 147;
        s_obs[im * 148 + r] = obs[(size_t)(base + im) * 147 + r];
    }
    __syncthreads();

    // ---- conv1 (fp32 VALU) ----
    {
        const int img = tid & 15;
        const float* ob = &s_obs[img * 148];
        for (int p = tid >> 4; p < 36; p += 16) {
            const int py = p / 6, px = p % 6;
            float o[12];
#pragma unroll
            for (int ky = 0; ky < 2; ky++)
#pragma unroll
                for (int kx = 0; kx < 2; kx++)
#pragma unroll
                    for (int cc = 0; cc < 3; cc++)
                        o[cc * 4 + ky * 2 + kx] = ob[((py + ky) * 7 + px + kx) * 3 + cc];
            unsigned short res[16];
#pragma unroll
            for (int ci = 0; ci < 16; ci++) {
                float a = b1s[ci];
#pragma unroll
                for (int q = 0; q < 12; q++) a = fmaf(o[q], w1s[ci * 12 + q], a);
                res[ci] = f2h(fmaxf(a, 0.0f));
            }
            *(ushort8v*)&c1s[img * 584 + p * 16]     = *(ushort8v*)&res[0];
            *(ushort8v*)&c1s[img * 584 + p * 16 + 8] = *(ushort8v*)&res[8];
        }
    }
    __syncthreads();

    // ---- conv2 (MFMA) ----
    {
        const int ct = wv & 1, par = wv >> 1;
        const int img = lane & 15, kq = lane >> 4;
        f16x8 wA[2];
        wA[0] = *(const f16x8*)&wb2g[(0 + ct) * 512 + lane * 8];
        wA[1] = *(const f16x8*)&wb2g[(2 + ct) * 512 + lane * 8];
        const float4 b2v = *(const float4*)&b2[ct * 16 + kq * 4];
#pragma unroll 2
        for (int p = par; p < 25; p += 2) {
            const int py = p / 5, px = p % 5;
            f32x4 acc = {0.f, 0.f, 0.f, 0.f};
#pragma unroll
            for (int ky = 0; ky < 2; ky++) {
                const int pix = (py + ky) * 6 + px + (kq >> 1);
                const f16x8 bv = *(const f16x8*)&c1s[img * 584 + pix * 16 + (kq & 1) * 8];
                acc = __builtin_amdgcn_mfma_f32_16x16x32_f16(wA[ky], bv, acc, 0, 0, 0);
            }
            unsigned short r4[4];
            r4[0] = f2h(fmaxf(acc[0] + b2v.x, 0.0f));
            r4[1] = f2h(fmaxf(acc[1] + b2v.y, 0.0f));
            r4[2] = f2h(fmaxf(acc[2] + b2v.z, 0.0f));
            r4[3] = f2h(fmaxf(acc[3] + b2v.w, 0.0f));
            *(ushort4v*)&c2s[img * 808 + p * 32 + ct * 16 + kq * 4] = *(ushort4v*)&r4[0];
        }
    }
    __syncthreads();

    // ---- conv3 (MFMA) ----
    {
        const int ct = wv;
        const int img = lane & 15, kq = lane >> 4;
        f16x8 wA3[4];
#pragma unroll
        for (int pos = 0; pos < 4; pos++)
            wA3[pos] = *(const f16x8*)&wb3g[(ct * 4 + pos) * 512 + lane * 8];
        const float4 b3v = *(const float4*)&b3[ct * 16 + kq * 4];
#pragma unroll 4
        for (int p = 0; p < 16; p++) {
            const int py = p >> 2, px = p & 3;
            f32x4 acc = {0.f, 0.f, 0.f, 0.f};
#pragma unroll
            for (int pos = 0; pos < 4; pos++) {
                const int pix = (py + (pos >> 1)) * 5 + px + (pos & 1);
                const f16x8 bv = *(const f16x8*)&c2s[img * 808 + pix * 32 + kq * 8];
                acc = __builtin_amdgcn_mfma_f32_16x16x32_f16(wA3[pos], bv, acc, 0, 0, 0);
            }
            unsigned short r4[4];
            r4[0] = f2h(fmaxf(acc[0] + b3v.x, 0.0f));
            r4[1] = f2h(fmaxf(acc[1] + b3v.y, 0.0f));
            r4[2] = f2h(fmaxf(acc[2] + b3v.z, 0.0f));
            r4[3] = f2h(fmaxf(acc[3] + b3v.w, 0.0f));
            *(ushort4v*)&c3s[img * 1032 + p * 64 + ct * 16 + kq * 4] = *(ushort4v*)&r4[0];
        }
    }
    __syncthreads();

#pragma unroll
    for (int i = 0; i < 8; i++) {
        const int gi = i * 2048 + tid * 8;
        const int img = gi >> 10, flat = gi & 1023;
        *(ushort8v*)&featb[(size_t)(base + img) * 1024 + flat] =
            *(const ushort8v*)&c3s[img * 1032 + flat];
    }
}

// ---------------------------------------------------------------------------
// K3: xperm = featb[32768,1024]_f16 @ wb[512,1024]_f16^T, permuted epilogue.
// ---------------------------------------------------------------------------
__global__ __launch_bounds__(256, 2) void gemm_xproj_mfma(
    const unsigned short* __restrict__ A,
    const unsigned short* __restrict__ W,
    float* __restrict__ Xp)
{
    __shared__ unsigned short As[128 * 32];
    __shared__ unsigned short Bs[128 * 32];

    const int tid  = threadIdx.x;
    const int bx = blockIdx.x & 3;
    const int by = blockIdx.x >> 2;
    const int m0 = by * 128, n0 = bx * 128;
    const int lane = tid & 63, wave = tid >> 6;
    const int wm = (wave >> 1) * 64, wn = (wave & 1) * 64;
    const int srow = tid >> 2, sseg = tid & 3;

    const unsigned short* Ag = A + (size_t)(m0 + srow) * 1024 + sseg * 8;
    const unsigned short* Wg = W + (size_t)(n0 + srow) * 1024 + sseg * 8;

    f32x4 acc[4][4];
#pragma unroll
    for (int i = 0; i < 4; i++)
#pragma unroll
        for (int j = 0; j < 4; j++) acc[i][j] = (f32x4){0.f, 0.f, 0.f, 0.f};

    const int fr = lane & 15, fq = lane >> 4;

    for (int k0 = 0; k0 < 1024; k0 += 32) {
        __syncthreads();
        GLDS16(Ag + k0,             (char*)As + tid * 16);
        GLDS16(Ag + k0 + 64 * 1024, (char*)As + tid * 16 + 4096);
        GLDS16(Wg + k0,             (char*)Bs + tid * 16);
        GLDS16(Wg + k0 + 64 * 1024, (char*)Bs + tid * 16 + 4096);
        __syncthreads();

        f16x8 af[4], bfv[4];
#pragma unroll
        for (int i = 0; i < 4; i++)
            af[i] = *(const f16x8*)&As[(wm + i * 16 + fr) * 32 + fq * 8];
#pragma unroll
        for (int j = 0; j < 4; j++)
            bfv[j] = *(const f16x8*)&Bs[(wn + j * 16 + fr) * 32 + fq * 8];
#pragma unroll
        for (int i = 0; i < 4; i++)
#pragma unroll
            for (int j = 0; j < 4; j++)
                acc[i][j] = __builtin_amdgcn_mfma_f32_16x16x32_f16(af[i], bfv[j], acc[i][j], 0, 0, 0);
    }

    // permuted epilogue (see header comment)
    const int cr = fq * 4, cc = fr;
#pragma unroll
    for (int i = 0; i < 4; i++) {
        const int m_base = m0 + wm + i * 16 + cr;       // + r, r=0..3
        const int t   = m_base >> 8;
        const int bhi = (m_base & 255) >> 4;            // constant over r
#pragma unroll
        for (int j = 0; j < 4; j++) {
            const int n  = n0 + wn + j * 16 + cc;
            const int gr = n >> 7, u = n & 127;
            const int w  = u >> 4, qt = (u >> 2) & 3, rr = u & 3;
            const size_t slot = (((size_t)(t * 16 + bhi) * 8 + w) * 64 + qt * 16);
#pragma unroll
            for (int r = 0; r < 4; r++)
                Xp[(slot + cr + r) * 16 + gr * 4 + rr] = acc[i][j][r];
        }
    }
}

// ---------------------------------------------------------------------------
// K4: LSTM, MFMA recurrence. 16 blocks x 512 thr (8 waves), 16 batch/block.
//   Wave w owns hid units [16w,16w+16); per step 16 MFMAs:
//   C[m=gate-in-tile][n=batch] = w_hh_frag (A) x h_frag (B), K=128 in 4 chunks.
//   Lane l (col=l&15=batch, q=l>>4): holds u0=16w+4q..+4, one batch col.
//   h stored k-major fp16 in LDS: h_s[(k>>3)*16 + batch][k&7] (4KB).
//   done-mask folded into h-writer (done[t+1]) and c (done[t]).
// ---------------------------------------------------------------------------
__global__ __launch_bounds__(512, 1) void lstm_kernel(
    const float* __restrict__ xperm, const float* __restrict__ done,
    const float* __restrict__ h0, const float* __restrict__ c0,
    const float* __restrict__ w_hh,
    const float* __restrict__ b_ih, const float* __restrict__ b_hh,
    float* __restrict__ hid, float* __restrict__ out)
{
    __shared__ __align__(16) unsigned short h_s[2048];

    const int tid = threadIdx.x, l = tid & 63, w = tid >> 6;
    const int col = l & 15, q = l >> 4;
    const int bb = blockIdx.x;
    const int b  = bb * 16 + col;
    const int u0 = 16 * w + q * 4;

    // w_hh fragments (A-operand): row m = l&15 within tile, k = q*8+j
    f16x8 wB[4][4];
#pragma unroll
    for (int tt = 0; tt < 4; tt++) {
        const int g = tt * 128 + 16 * w + col;
        const float* wr = w_hh + (size_t)g * 128 + q * 8;
#pragma unroll
        for (int kc = 0; kc < 4; kc++) {
            const float4 x = *(const float4*)&wr[kc * 32];
            const float4 y = *(const float4*)&wr[kc * 32 + 4];
            f16x8 f;
            f[0] = (_Float16)x.x; f[1] = (_Float16)x.y;
            f[2] = (_Float16)x.z; f[3] = (_Float16)x.w;
            f[4] = (_Float16)y.x; f[5] = (_Float16)y.y;
            f[6] = (_Float16)y.z; f[7] = (_Float16)y.w;
            wB[tt][kc] = f;
        }
    }

    // biases for this lane's 4 units per gate group
    float4 bias4[4];
#pragma unroll
    for (int tt = 0; tt < 4; tt++) {
        const int g0 = tt * 128 + u0;
        const float4 bi = *(const float4*)&b_ih[g0];
        const float4 bh = *(const float4*)&b_hh[g0];
        bias4[tt] = make_float4(bi.x + bh.x, bi.y + bh.y, bi.z + bh.z, bi.w + bh.w);
    }

    // state
    float4 c   = *(const float4*)&c0[(size_t)b * 128 + u0];
    float4 h0v = *(const float4*)&h0[(size_t)b * 128 + u0];
    float dcur = done[b];                       // done[0][b]
    const int hsSlot = ((u0 >> 3) * 16 + col) * 8 + (u0 & 7);

    {   // init h_s with done[0]-masked h0
        const float m0v = 1.0f - dcur;
        unsigned short hh[4];
        hh[0] = f2h(h0v.x * m0v); hh[1] = f2h(h0v.y * m0v);
        hh[2] = f2h(h0v.z * m0v); hh[3] = f2h(h0v.w * m0v);
        *(ushort4v*)&h_s[hsSlot] = *(ushort4v*)hh;
    }

    // preload xp(t=0)
    float4 xp[4];
    {
        const float* xb = xperm + (((size_t)(0 * 16 + bb) * 8 + w) * 64 + l) * 16;
#pragma unroll
        for (int tt = 0; tt < 4; tt++) xp[tt] = *(const float4*)&xb[tt * 4];
    }

    float4 hcur = h0v;

    for (int t = 0; t < T_LEN; t++) {
        __syncthreads();                         // h_s ready for step t

        // h fragments (B-operand): n = col, k = kc*32 + q*8
        f16x8 hf[4];
#pragma unroll
        for (int kc = 0; kc < 4; kc++)
            hf[kc] = *(const f16x8*)&h_s[((kc * 4 + q) * 16 + col) * 8];

        // prefetch next step
        const int tn = (t < T_LEN - 1) ? t + 1 : T_LEN - 1;
        float4 xpn[4];
        const float* xbn = xperm + (((size_t)(tn * 16 + bb) * 8 + w) * 64 + l) * 16;
#pragma unroll
        for (int tt = 0; tt < 4; tt++) xpn[tt] = *(const float4*)&xbn[tt * 4];
        const float dnext = done[tn * B_ENV + b];

        // gates
        f32x4 acc[4];
#pragma unroll
        for (int tt = 0; tt < 4; tt++) {
            acc[tt] = (f32x4){xp[tt].x + bias4[tt].x, xp[tt].y + bias4[tt].y,
                              xp[tt].z + bias4[tt].z, xp[tt].w + bias4[tt].w};
#pragma unroll
            for (int kc = 0; kc < 4; kc++)
                acc[tt] = __builtin_amdgcn_mfma_f32_16x16x32_f16(wB[tt][kc], hf[kc], acc[tt], 0, 0, 0);
        }

        // c-mask (done[t]) + activations + update
        const float mc = 1.0f - dcur;
        float cv[4] = {c.x * mc, c.y * mc, c.z * mc, c.w * mc};
        float hv[4];
#pragma unroll
        for (int rr = 0; rr < 4; rr++) {
            const float ig = sigm_(acc[0][rr]);
            const float fg = sigm_(acc[1][rr]);
            const float gg = tanh_(acc[2][rr]);
            const float og = sigm_(acc[3][rr]);
            const float cn = fmaf(fg, cv[rr], ig * gg);
            cv[rr] = cn;
            hv[rr] = og * tanh_(cn);
        }
        c = make_float4(cv[0], cv[1], cv[2], cv[3]);
        hcur = make_float4(hv[0], hv[1], hv[2], hv[3]);

        // store hid (unmasked)
        *(float4*)&hid[((size_t)t * B_ENV + b) * 128 + u0] = hcur;

        __syncthreads();                         // all reads of h_s(t) done

        // write h for step t+1, pre-masked with done[t+1]
        const float mh = (t < T_LEN - 1) ? (1.0f - dnext) : 1.0f;
        unsigned short hh[4];
        hh[0] = f2h(hv[0] * mh); hh[1] = f2h(hv[1] * mh);
        hh[2] = f2h(hv[2] * mh); hh[3] = f2h(hv[3] * mh);
        *(ushort4v*)&h_s[hsSlot] = *(ushort4v*)hh;

#pragma unroll
        for (int tt = 0; tt < 4; tt++) xp[tt] = xpn[tt];
        dcur = dnext;
    }

    *(float4*)&out[262144 + (size_t)b * 128 + u0] = hcur;   // hT
    *(float4*)&out[294912 + (size_t)b * 128 + u0] = c;      // cT
}

// ---------------------------------------------------------------------------
// K5: heads. out[n][0..6] = actor, out[n][7] = critic. 32 rows / block.
// ---------------------------------------------------------------------------
__global__ __launch_bounds__(256, 2) void heads_kernel(
    const float* __restrict__ hid,
    const float* __restrict__ aw, const float* __restrict__ ab,
    const float* __restrict__ cw, const float* __restrict__ cb,
    float* __restrict__ out)
{
    __shared__ float hs[32 * 129];
    __shared__ float ws[8 * 130];
    __shared__ float bs[8];

    const int tid = threadIdx.x;
    const int n0 = blockIdx.x * 32;

    for (int i = tid; i < 1024; i += 256) {
        const int r = i >> 7, k = i & 127;
        ws[r * 130 + k] = (r < 7) ? aw[r * 128 + k] : cw[k];
    }
    if (tid < 8) bs[tid] = (tid < 7) ? ab[tid] : cb[0];
    for (int i = tid; i < 4096; i += 256) {
        const int r = i >> 7, k = i & 127;
        hs[r * 129 + k] = hid[(size_t)(n0 + r) * 128 + k];
    }
    __syncthreads();

    const int r = tid >> 3, jj = tid & 7;
    float acc = bs[jj];
    const float* hp = &hs[r * 129];
    const float* wp = &ws[jj * 130];
#pragma unroll
    for (int k = 0; k < 128; k++) acc = fmaf(hp[k], wp[k], acc);
    out[(size_t)(n0 + r) * 8 + jj] = acc;
}

// ---------------------------------------------------------------------------
extern "C" void kernel_launch(void* const* d_in, const int* in_sizes, int n_in,
                              void* d_out, int out_size, void* d_ws, size_t ws_size,
                              hipStream_t stream)
{
    (void)in_sizes; (void)n_in; (void)out_size; (void)ws_size;

    const float* obs  = (const float*)d_in[0];
    const float* done = (const float*)d_in[1];
    const float* h0   = (const float*)d_in[2];
    const float* c0   = (const float*)d_in[3];
    const float* w1   = (const float*)d_in[4];
    const float* b1   = (const float*)d_in[5];
    const float* w2   = (const float*)d_in[6];
    const float* b2   = (const float*)d_in[7];
    const float* w3   = (const float*)d_in[8];
    const float* b3   = (const float*)d_in[9];
    const float* w_ih = (const float*)d_in[10];
    const float* w_hh = (const float*)d_in[11];
    const float* b_ih = (const float*)d_in[12];
    const float* b_hh = (const float*)d_in[13];
    const float* aw   = (const float*)d_in[14];
    const float* ab   = (const float*)d_in[15];
    const float* cw   = (const float*)d_in[16];
    const float* cb   = (const float*)d_in[17];
    float* out = (float*)d_out;

    unsigned short* featb = (unsigned short*)d_ws;     // 33,554,432 u16
    unsigned short* wb    = featb + 33554432ull;       //    524,288 u16
    unsigned short* wb2g  = wb    + 524288ull;         //      2,048 u16
    unsigned short* wb3g  = wb2g  + 2048ull;           //      8,192 u16
    float* xperm = (float*)(wb3g + 8192ull + 2048ull); // 16,777,216 f32
    float* hid   = xperm + 16777216ull;                //  4,194,304 f32

    prep_wih<<<2048, 256, 0, stream>>>(w_ih, wb);
    prep_convw<<<40, 256, 0, stream>>>(w2, w3, wb2g, wb3g);
    conv_fused<<<2048, 256, 0, stream>>>(obs, w1, b1, b2, b3, wb2g, wb3g, featb);
    gemm_xproj_mfma<<<1024, 256, 0, stream>>>(featb, wb, xperm);
    lstm_kernel<<<16, 512, 0, stream>>>(xperm, done, h0, c0, w_hh, b_ih, b_hh, hid, out);
    heads_kernel<<<1024, 256, 0, stream>>>(hid, aw, ab, cw, cb, out);
}

// Round 5
// 417.697 us; speedup vs baseline: 1.1732x; 1.1732x over previous
//
#include <hip/hip_runtime.h>
#include <hip/hip_bf16.h>

// ---------------------------------------------------------------------------
// MinigridPPOLSTMAgent forward, round 5: latency-lean MFMA LSTM.
//   T=128, B=256, N=32768, HID=128, NFLAT=1024, NA=7
// Pipeline:
//   P1 prep_wih   : w_ih fp32 [512][co*16+p] -> fp16 wb[512][p*64+co] (K-perm)
//   P2 prep_convw : w2/w3 -> MFMA A-fragment-ordered fp16 tables
//   K1 conv_fused : obs -> featb[N][p*64+co] fp16 (conv2/3 via MFMA)
//   K3 gemm_mfma  : xperm = featb @ wb^T, coalesced permuted epilogue
//   K4 lstm       : 16 blocks x 512thr; MFMA recurrence; double-buffered h_s,
//                   ONE raw s_barrier/step (lgkmcnt-only wait -> vmem stays
//                   in flight), done in LDS, 2-deep xperm register prefetch
//   K5 heads      : out[N,8] = hid @ [actor;critic].T + b
//
// xperm layout: value for (t, batch b, gate g):
//   bb=b>>4, col=b&15, gr=g>>7, wl=(g>>4)&7, glow=g&15
//   addr = (((t*16+bb)*8 + wl)*16 + col)*64 + gr*16 + glow
//   GEMM store: across a wave, glow=fr (minor 16, contiguous 64B segments).
//   LSTM lane (w,q,col): 4 x float4 at base + col*64 + q*4 + gr*16.
// ---------------------------------------------------------------------------

#define N_IMG   32768
#define T_LEN   128
#define B_ENV   256
#define HID     128

typedef _Float16 f16x8 __attribute__((ext_vector_type(8)));
typedef float    f32x4 __attribute__((ext_vector_type(4)));
typedef unsigned short ushort8v __attribute__((ext_vector_type(8)));
typedef unsigned short ushort4v __attribute__((ext_vector_type(4)));

__device__ __forceinline__ float sigm_(float x) { return 1.0f / (1.0f + __expf(-x)); }
__device__ __forceinline__ float tanh_(float x) { return 2.0f / (1.0f + __expf(-2.0f * x)) - 1.0f; }

__device__ __forceinline__ unsigned short f2h(float x) {
    union { _Float16 h; unsigned short u; } un; un.h = (_Float16)x;
    return un.u;
}

#define GLDS16(g, l) __builtin_amdgcn_global_load_lds( \
    (const __attribute__((address_space(1))) unsigned int*)(g), \
    (__attribute__((address_space(3))) unsigned int*)(l), 16, 0, 0)

// ---------------------------------------------------------------------------
// P1: w_ih fp32 [n][k=co*16+p] -> fp16 wb[n][k'=p*64+co]
// ---------------------------------------------------------------------------
__global__ void prep_wih(const float* __restrict__ w, unsigned short* __restrict__ wb)
{
    const int idx = blockIdx.x * 256 + threadIdx.x;   // < 524288
    const int n = idx >> 10, kk = idx & 1023;
    const int p = kk >> 6, co = kk & 63;
    wb[idx] = f2h(w[n * 1024 + co * 16 + p]);
}

// ---------------------------------------------------------------------------
// P2: conv2/conv3 weights -> MFMA A-fragment layout (fp16)
// ---------------------------------------------------------------------------
__global__ void prep_convw(const float* __restrict__ w2, const float* __restrict__ w3,
                           unsigned short* __restrict__ wb2g, unsigned short* __restrict__ wb3g)
{
    const int t = blockIdx.x * 256 + threadIdx.x;     // < 10240
    if (t < 2048) {
        const int j = t & 7, lane = (t >> 3) & 63, f = t >> 9;   // f = ky*2+ct
        const int ky = f >> 1, ct = f & 1;
        const int k = ((lane >> 4) << 3) + j, kx = k >> 4, ci = k & 15;
        wb2g[t] = f2h(w2[(ct * 16 + (lane & 15)) * 64 + ci * 4 + ky * 2 + kx]);
    } else if (t < 10240) {
        const int u = t - 2048;
        const int j = u & 7, lane = (u >> 3) & 63, f = u >> 9;   // f = ct*4+pos
        const int ct = f >> 2, pos = f & 3;
        const int ci = ((lane >> 4) << 3) + j;
        wb3g[u] = f2h(w3[(ct * 16 + (lane & 15)) * 128 + ci * 4 + pos]);
    }
}

// ---------------------------------------------------------------------------
// K1: fused conv. 16 images / block, 2048 blocks, 256 thr (4 waves).
// ---------------------------------------------------------------------------
__global__ __launch_bounds__(256, 2) void conv_fused(
    const float* __restrict__ obs,
    const float* __restrict__ w1, const float* __restrict__ b1,
    const float* __restrict__ b2, const float* __restrict__ b3,
    const unsigned short* __restrict__ wb2g,
    const unsigned short* __restrict__ wb3g,
    unsigned short* __restrict__ featb)
{
    __shared__ __align__(16) unsigned char u1[25856];   // max(obs 9472, c2s 25856)
    __shared__ __align__(16) unsigned char u2[33024];   // max(c1s 18688, c3s 33024)
    __shared__ float w1s[192];
    __shared__ float b1s[16];

    float* s_obs = (float*)u1;                 // [img][148]
    unsigned short* c2s = (unsigned short*)u1; // [img][pix*32+ci], img stride 808
    unsigned short* c1s = (unsigned short*)u2; // [img][p*16+ci],  img stride 584
    unsigned short* c3s = (unsigned short*)u2; // [img][p*64+co],  img stride 1032

    const int tid = threadIdx.x, lane = tid & 63, wv = tid >> 6;
    const int base = blockIdx.x * 16;

    if (tid < 192) w1s[tid] = w1[tid];
    if (tid < 16)  b1s[tid] = b1[tid];
    for (int i = tid; i < 16 * 147; i += 256) {
        const int im = i / 147, r = i - im * 147;
        s_obs[im * 148 + r] = obs[(size_t)(base + im) * 147 + r];
    }
    __syncthreads();

    // ---- conv1 (fp32 VALU) ----
    {
        const int img = tid & 15;
        const float* ob = &s_obs[img * 148];
        for (int p = tid >> 4; p < 36; p += 16) {
            const int py = p / 6, px = p % 6;
            float o[12];
#pragma unroll
            for (int ky = 0; ky < 2; ky++)
#pragma unroll
                for (int kx = 0; kx < 2; kx++)
#pragma unroll
                    for (int cc = 0; cc < 3; cc++)
                        o[cc * 4 + ky * 2 + kx] = ob[((py + ky) * 7 + px + kx) * 3 + cc];
            unsigned short res[16];
#pragma unroll
            for (int ci = 0; ci < 16; ci++) {
                float a = b1s[ci];
#pragma unroll
                for (int q = 0; q < 12; q++) a = fmaf(o[q], w1s[ci * 12 + q], a);
                res[ci] = f2h(fmaxf(a, 0.0f));
            }
            *(ushort8v*)&c1s[img * 584 + p * 16]     = *(ushort8v*)&res[0];
            *(ushort8v*)&c1s[img * 584 + p * 16 + 8] = *(ushort8v*)&res[8];
        }
    }
    __syncthreads();

    // ---- conv2 (MFMA) ----
    {
        const int ct = wv & 1, par = wv >> 1;
        const int img = lane & 15, kq = lane >> 4;
        f16x8 wA[2];
        wA[0] = *(const f16x8*)&wb2g[(0 + ct) * 512 + lane * 8];
        wA[1] = *(const f16x8*)&wb2g[(2 + ct) * 512 + lane * 8];
        const float4 b2v = *(const float4*)&b2[ct * 16 + kq * 4];
#pragma unroll 2
        for (int p = par; p < 25; p += 2) {
            const int py = p / 5, px = p % 5;
            f32x4 acc = {0.f, 0.f, 0.f, 0.f};
#pragma unroll
            for (int ky = 0; ky < 2; ky++) {
                const int pix = (py + ky) * 6 + px + (kq >> 1);
                const f16x8 bv = *(const f16x8*)&c1s[img * 584 + pix * 16 + (kq & 1) * 8];
                acc = __builtin_amdgcn_mfma_f32_16x16x32_f16(wA[ky], bv, acc, 0, 0, 0);
            }
            unsigned short r4[4];
            r4[0] = f2h(fmaxf(acc[0] + b2v.x, 0.0f));
            r4[1] = f2h(fmaxf(acc[1] + b2v.y, 0.0f));
            r4[2] = f2h(fmaxf(acc[2] + b2v.z, 0.0f));
            r4[3] = f2h(fmaxf(acc[3] + b2v.w, 0.0f));
            *(ushort4v*)&c2s[img * 808 + p * 32 + ct * 16 + kq * 4] = *(ushort4v*)&r4[0];
        }
    }
    __syncthreads();

    // ---- conv3 (MFMA) ----
    {
        const int ct = wv;
        const int img = lane & 15, kq = lane >> 4;
        f16x8 wA3[4];
#pragma unroll
        for (int pos = 0; pos < 4; pos++)
            wA3[pos] = *(const f16x8*)&wb3g[(ct * 4 + pos) * 512 + lane * 8];
        const float4 b3v = *(const float4*)&b3[ct * 16 + kq * 4];
#pragma unroll 4
        for (int p = 0; p < 16; p++) {
            const int py = p >> 2, px = p & 3;
            f32x4 acc = {0.f, 0.f, 0.f, 0.f};
#pragma unroll
            for (int pos = 0; pos < 4; pos++) {
                const int pix = (py + (pos >> 1)) * 5 + px + (pos & 1);
                const f16x8 bv = *(const f16x8*)&c2s[img * 808 + pix * 32 + kq * 8];
                acc = __builtin_amdgcn_mfma_f32_16x16x32_f16(wA3[pos], bv, acc, 0, 0, 0);
            }
            unsigned short r4[4];
            r4[0] = f2h(fmaxf(acc[0] + b3v.x, 0.0f));
            r4[1] = f2h(fmaxf(acc[1] + b3v.y, 0.0f));
            r4[2] = f2h(fmaxf(acc[2] + b3v.z, 0.0f));
            r4[3] = f2h(fmaxf(acc[3] + b3v.w, 0.0f));
            *(ushort4v*)&c3s[img * 1032 + p * 64 + ct * 16 + kq * 4] = *(ushort4v*)&r4[0];
        }
    }
    __syncthreads();

#pragma unroll
    for (int i = 0; i < 8; i++) {
        const int gi = i * 2048 + tid * 8;
        const int img = gi >> 10, flat = gi & 1023;
        *(ushort8v*)&featb[(size_t)(base + img) * 1024 + flat] =
            *(const ushort8v*)&c3s[img * 1032 + flat];
    }
}

// ---------------------------------------------------------------------------
// K3: xperm = featb[32768,1024]_f16 @ wb[512,1024]_f16^T, coalesced permuted
//   epilogue (addr = ((m>>4)*128 + wl*16 + m&15)*64 + gr*16 + fr).
// ---------------------------------------------------------------------------
__global__ __launch_bounds__(256, 2) void gemm_xproj_mfma(
    const unsigned short* __restrict__ A,
    const unsigned short* __restrict__ W,
    float* __restrict__ Xp)
{
    __shared__ unsigned short As[128 * 32];
    __shared__ unsigned short Bs[128 * 32];

    const int tid  = threadIdx.x;
    const int bx = blockIdx.x & 3;
    const int by = blockIdx.x >> 2;
    const int m0 = by * 128, n0 = bx * 128;
    const int lane = tid & 63, wave = tid >> 6;
    const int wm = (wave >> 1) * 64, wn = (wave & 1) * 64;
    const int srow = tid >> 2, sseg = tid & 3;

    const unsigned short* Ag = A + (size_t)(m0 + srow) * 1024 + sseg * 8;
    const unsigned short* Wg = W + (size_t)(n0 + srow) * 1024 + sseg * 8;

    f32x4 acc[4][4];
#pragma unroll
    for (int i = 0; i < 4; i++)
#pragma unroll
        for (int j = 0; j < 4; j++) acc[i][j] = (f32x4){0.f, 0.f, 0.f, 0.f};

    const int fr = lane & 15, fq = lane >> 4;

    for (int k0 = 0; k0 < 1024; k0 += 32) {
        __syncthreads();
        GLDS16(Ag + k0,             (char*)As + tid * 16);
        GLDS16(Ag + k0 + 64 * 1024, (char*)As + tid * 16 + 4096);
        GLDS16(Wg + k0,             (char*)Bs + tid * 16);
        GLDS16(Wg + k0 + 64 * 1024, (char*)Bs + tid * 16 + 4096);
        __syncthreads();

        f16x8 af[4], bfv[4];
#pragma unroll
        for (int i = 0; i < 4; i++)
            af[i] = *(const f16x8*)&As[(wm + i * 16 + fr) * 32 + fq * 8];
#pragma unroll
        for (int j = 0; j < 4; j++)
            bfv[j] = *(const f16x8*)&Bs[(wn + j * 16 + fr) * 32 + fq * 8];
#pragma unroll
        for (int i = 0; i < 4; i++)
#pragma unroll
            for (int j = 0; j < 4; j++)
                acc[i][j] = __builtin_amdgcn_mfma_f32_16x16x32_f16(af[i], bfv[j], acc[i][j], 0, 0, 0);
    }

    // coalesced permuted epilogue: glow = fr is the minor-16 dimension
#pragma unroll
    for (int j = 0; j < 4; j++) {
        const int g  = n0 + wn + j * 16 + fr;
        const int gr = g >> 7, wl = (g >> 4) & 7;
        const int joff = wl * 16 * 64 + gr * 16 + fr;     // wl,gr const over r; fr minor
#pragma unroll
        for (int i = 0; i < 4; i++) {
            const int mb = m0 + wm + i * 16;              // multiple of 16
            const size_t basea = (size_t)((mb >> 4) * 128) * 64 + joff + fq * 256;
#pragma unroll
            for (int r = 0; r < 4; r++)
                Xp[basea + r * 64] = acc[i][j][r];
        }
    }
}

// ---------------------------------------------------------------------------
// K4: LSTM, MFMA recurrence, latency-lean.
//   16 blocks x 512 thr (8 waves), 16 batch/block. Wave w owns units
//   [16w,16w+16); lane l: col=l&15 (batch), q=l>>4, units u0=16w+4q..+3.
//   h double-buffered k-major fp16 in LDS; ONE raw s_barrier per step with
//   lgkmcnt-only wait (hid stores + xperm prefetch stay in flight).
//   done pre-staged in LDS. xperm register-prefetched 2 steps deep.
// ---------------------------------------------------------------------------
__global__ __launch_bounds__(512, 2) void lstm_kernel(
    const float* __restrict__ xperm, const float* __restrict__ done,
    const float* __restrict__ h0, const float* __restrict__ c0,
    const float* __restrict__ w_hh,
    const float* __restrict__ b_ih, const float* __restrict__ b_hh,
    float* __restrict__ hid, float* __restrict__ out)
{
    __shared__ __align__(16) unsigned short h_sb[2][2048];
    __shared__ float done_s[T_LEN * 16];

    const int tid = threadIdx.x, l = tid & 63, w = tid >> 6;
    const int col = l & 15, q = l >> 4;
    const int bb = blockIdx.x;
    const int b  = bb * 16 + col;
    const int u0 = 16 * w + q * 4;

    // stage done into LDS (8 KB)
    for (int i = tid; i < T_LEN * 16; i += 512)
        done_s[i] = done[(i >> 4) * B_ENV + bb * 16 + (i & 15)];

    // w_hh fragments (A-operand): m=col within tile, k=kc*32+q*8+j
    f16x8 wB[4][4];
#pragma unroll
    for (int tt = 0; tt < 4; tt++) {
        const int g = tt * 128 + 16 * w + col;
        const float* wr = w_hh + (size_t)g * 128 + q * 8;
#pragma unroll
        for (int kc = 0; kc < 4; kc++) {
            const float4 x = *(const float4*)&wr[kc * 32];
            const float4 y = *(const float4*)&wr[kc * 32 + 4];
            f16x8 f;
            f[0] = (_Float16)x.x; f[1] = (_Float16)x.y;
            f[2] = (_Float16)x.z; f[3] = (_Float16)x.w;
            f[4] = (_Float16)y.x; f[5] = (_Float16)y.y;
            f[6] = (_Float16)y.z; f[7] = (_Float16)y.w;
            wB[tt][kc] = f;
        }
    }

    float4 bias4[4];
#pragma unroll
    for (int tt = 0; tt < 4; tt++) {
        const int g0 = tt * 128 + u0;
        const float4 bi = *(const float4*)&b_ih[g0];
        const float4 bh = *(const float4*)&b_hh[g0];
        bias4[tt] = make_float4(bi.x + bh.x, bi.y + bh.y, bi.z + bh.z, bi.w + bh.w);
    }

    float4 c   = *(const float4*)&c0[(size_t)b * 128 + u0];
    float4 h0v = *(const float4*)&h0[(size_t)b * 128 + u0];
    const int hsSlot = ((u0 >> 3) * 16 + col) * 8 + (u0 & 7);

    {   // init h_sb[0] with done[0]-masked h0
        const float m0v = 1.0f - done[b];
        unsigned short hh[4];
        hh[0] = f2h(h0v.x * m0v); hh[1] = f2h(h0v.y * m0v);
        hh[2] = f2h(h0v.z * m0v); hh[3] = f2h(h0v.w * m0v);
        *(ushort4v*)&h_sb[0][hsSlot] = *(ushort4v*)hh;
    }

    // 2-deep xperm prefetch
    const size_t laneoff = (size_t)col * 64 + q * 4;
    float4 xA[4], xB[4];
    {
        const float* p0 = xperm + ((size_t)(0 * 16 + bb) * 8 + w) * 1024 + laneoff;
        const float* p1 = xperm + ((size_t)(1 * 16 + bb) * 8 + w) * 1024 + laneoff;
#pragma unroll
        for (int gr = 0; gr < 4; gr++) {
            xA[gr] = *(const float4*)&p0[gr * 16];
            xB[gr] = *(const float4*)&p1[gr * 16];
        }
    }

    __syncthreads();   // h_sb[0], done_s ready (full barrier once, pre-loop)

    float4 hcur = h0v;

#pragma unroll 2
    for (int t = 0; t < T_LEN; t++) {
        // h fragments (B-operand) from buffer t&1
        const unsigned short* hb = h_sb[t & 1];
        f16x8 hf[4];
#pragma unroll
        for (int kc = 0; kc < 4; kc++)
            hf[kc] = *(const f16x8*)&hb[((kc * 4 + q) * 16 + col) * 8];

        // issue prefetch for t+2 (clamped)
        const int tp = (t + 2 < T_LEN) ? t + 2 : T_LEN - 1;
        float4 xN[4];
        {
            const float* pn = xperm + ((size_t)(tp * 16 + bb) * 8 + w) * 1024 + laneoff;
#pragma unroll
            for (int gr = 0; gr < 4; gr++) xN[gr] = *(const float4*)&pn[gr * 16];
        }

        // gates
        f32x4 acc[4];
#pragma unroll
        for (int tt = 0; tt < 4; tt++) {
            acc[tt] = (f32x4){xA[tt].x + bias4[tt].x, xA[tt].y + bias4[tt].y,
                              xA[tt].z + bias4[tt].z, xA[tt].w + bias4[tt].w};
#pragma unroll
            for (int kc = 0; kc < 4; kc++)
                acc[tt] = __builtin_amdgcn_mfma_f32_16x16x32_f16(wB[tt][kc], hf[kc], acc[tt], 0, 0, 0);
        }

        // activations + state update (c-mask uses done[t])
        const float mc = 1.0f - done_s[t * 16 + col];
        float cv[4] = {c.x * mc, c.y * mc, c.z * mc, c.w * mc};
        float hv[4];
#pragma unroll
        for (int rr = 0; rr < 4; rr++) {
            const float ig = sigm_(acc[0][rr]);
            const float fg = sigm_(acc[1][rr]);
            const float gg = tanh_(acc[2][rr]);
            const float og = sigm_(acc[3][rr]);
            const float cn = fmaf(fg, cv[rr], ig * gg);
            cv[rr] = cn;
            hv[rr] = og * tanh_(cn);
        }
        c = make_float4(cv[0], cv[1], cv[2], cv[3]);
        hcur = make_float4(hv[0], hv[1], hv[2], hv[3]);

        // store hid (fire-and-forget; never drained in-loop)
        *(float4*)&hid[((size_t)t * B_ENV + b) * 128 + u0] = hcur;

        // write h(t+1) into the other buffer, pre-masked with done[t+1]
        const float dnx = done_s[((t + 1 < T_LEN) ? t + 1 : t) * 16 + col];
        const float mh = (t < T_LEN - 1) ? (1.0f - dnx) : 1.0f;
        unsigned short hh[4];
        hh[0] = f2h(hv[0] * mh); hh[1] = f2h(hv[1] * mh);
        hh[2] = f2h(hv[2] * mh); hh[3] = f2h(hv[3] * mh);
        *(ushort4v*)&h_sb[(t + 1) & 1][hsSlot] = *(ushort4v*)hh;

        // ONE raw barrier: wait LDS only; vmem stays outstanding
        asm volatile("s_waitcnt lgkmcnt(0)" ::: "memory");
        __builtin_amdgcn_s_barrier();
        asm volatile("" ::: "memory");

        // rotate prefetch registers
#pragma unroll
        for (int gr = 0; gr < 4; gr++) { xA[gr] = xB[gr]; xB[gr] = xN[gr]; }
    }

    *(float4*)&out[262144 + (size_t)b * 128 + u0] = hcur;   // hT
    *(float4*)&out[294912 + (size_t)b * 128 + u0] = c;      // cT
}

// ---------------------------------------------------------------------------
// K5: heads. out[n][0..6] = actor, out[n][7] = critic. 32 rows / block.
// ---------------------------------------------------------------------------
__global__ __launch_bounds__(256, 2) void heads_kernel(
    const float* __restrict__ hid,
    const float* __restrict__ aw, const float* __restrict__ ab,
    const float* __restrict__ cw, const float* __restrict__ cb,
    float* __restrict__ out)
{
    __shared__ float hs[32 * 129];
    __shared__ float ws[8 * 130];
    __shared__ float bs[8];

    const int tid = threadIdx.x;
    const int n0 = blockIdx.x * 32;

    for (int i = tid; i < 1024; i += 256) {
        const int r = i >> 7, k = i & 127;
        ws[r * 130 + k] = (r < 7) ? aw[r * 128 + k] : cw[k];
    }
    if (tid < 8) bs[tid] = (tid < 7) ? ab[tid] : cb[0];
    for (int i = tid; i < 4096; i += 256) {
        const int r = i >> 7, k = i & 127;
        hs[r * 129 + k] = hid[(size_t)(n0 + r) * 128 + k];
    }
    __syncthreads();

    const int r = tid >> 3, jj = tid & 7;
    float acc = bs[jj];
    const float* hp = &hs[r * 129];
    const float* wp = &ws[jj * 130];
#pragma unroll
    for (int k = 0; k < 128; k++) acc = fmaf(hp[k], wp[k], acc);
    out[(size_t)(n0 + r) * 8 + jj] = acc;
}

// ---------------------------------------------------------------------------
extern "C" void kernel_launch(void* const* d_in, const int* in_sizes, int n_in,
                              void* d_out, int out_size, void* d_ws, size_t ws_size,
                              hipStream_t stream)
{
    (void)in_sizes; (void)n_in; (void)out_size; (void)ws_size;

    const float* obs  = (const float*)d_in[0];
    const float* done = (const float*)d_in[1];
    const float* h0   = (const float*)d_in[2];
    const float* c0   = (const float*)d_in[3];
    const float* w1   = (const float*)d_in[4];
    const float* b1   = (const float*)d_in[5];
    const float* w2   = (const float*)d_in[6];
    const float* b2   = (const float*)d_in[7];
    const float* w3   = (const float*)d_in[8];
    const float* b3   = (const float*)d_in[9];
    const float* w_ih = (const float*)d_in[10];
    const float* w_hh = (const float*)d_in[11];
    const float* b_ih = (const float*)d_in[12];
    const float* b_hh = (const float*)d_in[13];
    const float* aw   = (const float*)d_in[14];
    const float* ab   = (const float*)d_in[15];
    const float* cw   = (const float*)d_in[16];
    const float* cb   = (const float*)d_in[17];
    float* out = (float*)d_out;

    unsigned short* featb = (unsigned short*)d_ws;     // 33,554,432 u16
    unsigned short* wb    = featb + 33554432ull;       //    524,288 u16
    unsigned short* wb2g  = wb    + 524288ull;         //      2,048 u16
    unsigned short* wb3g  = wb2g  + 2048ull;           //      8,192 u16
    float* xperm = (float*)(wb3g + 8192ull + 2048ull); // 16,777,216 f32
    float* hid   = xperm + 16777216ull;                //  4,194,304 f32

    prep_wih<<<2048, 256, 0, stream>>>(w_ih, wb);
    prep_convw<<<40, 256, 0, stream>>>(w2, w3, wb2g, wb3g);
    conv_fused<<<2048, 256, 0, stream>>>(obs, w1, b1, b2, b3, wb2g, wb3g, featb);
    gemm_xproj_mfma<<<1024, 256, 0, stream>>>(featb, wb, xperm);
    lstm_kernel<<<16, 512, 0, stream>>>(xperm, done, h0, c0, w_hh, b_ih, b_hh, hid, out);
    heads_kernel<<<1024, 256, 0, stream>>>(hid, aw, ab, cw, cb, out);
}